// Round 3
// baseline (50.169 us; speedup 1.0000x reference)
//
#include <hip/hip_runtime.h>

#define NPIX (512*512)
#define MS 620   // M per-pixel LDS stride (floats): 22 j * 28 k-words = 616, +4 pad (MS/4 odd -> even bank spread)
#define ZS 252   // z per-pixel LDS stride: 9 nb * 28 k-words

// ---------------------------------------------------------------------------
// Init kernel: coef[path][a][b][kq] = 0.5 * tp_w * Cr  (padded k-runs: 12/16).
// Path offsets (floats): {0,972,2268,3672,5544,6948,8820,10848}, 13552 total.
// ---------------------------------------------------------------------------

static __device__ __forceinline__ int qcol(int l, int c, int* row, double* re, double* im) {
  const double S = 0.70710678118654752440;
  int p = c - l;
  if (p == 0) { row[0] = l; re[0] = 1.0; im[0] = 0.0; return 1; }
  if (p > 0) {
    row[0] = l - p; re[0] = S;                 im[0] = 0.0;
    row[1] = l + p; re[1] = (p & 1) ? -S : S;  im[1] = 0.0;
    return 2;
  }
  int a = -p;
  row[0] = l - a; re[0] = 0.0; im[0] = -S;
  row[1] = l + a; re[1] = 0.0; im[1] = (a & 1) ? -S : S;
  return 2;
}

__global__ void w3j_init(const float* __restrict__ tpw, float* __restrict__ coef) {
  __shared__ double sC[13*13*13];
  __shared__ double sfact[20];
  const int p = blockIdx.x;
  const int la = (p & 4) ? 6 : 4, lb = (p & 2) ? 6 : 4, lc = (p & 1) ? 6 : 4;
  const int na = 2*la+1, nb = 2*lb+1, nc = 2*lc+1, ncp = (nc + 3) & ~3;
  if (threadIdx.x == 0) {
    double f = 1.0; sfact[0] = 1.0;
    for (int i = 1; i < 20; ++i) { f *= (double)i; sfact[i] = f; }
  }
  int off = 0;
  for (int q = 0; q < p; ++q)
    off += ((q&4)?13:9) * ((q&2)?13:9) * ((q&1)?16:12);
  for (int e = threadIdx.x; e < na*nb*nc; e += blockDim.x) sC[e] = 0.0;
  __syncthreads();
  for (int e = threadIdx.x; e < na*nb; e += blockDim.x) {
    int i = e / nb, j = e % nb;
    int m1 = i - la, m2 = j - lb, m3 = m1 + m2;
    if (m3 < -lc || m3 > lc) continue;
    double pre = sqrt((2.0*lc + 1.0) * sfact[lc+la-lb] * sfact[lc-la+lb] * sfact[la+lb-lc] / sfact[la+lb+lc+1]);
    pre *= sqrt(sfact[lc+m3]*sfact[lc-m3]*sfact[la-m1]*sfact[la+m1]*sfact[lb-m2]*sfact[lb+m2]);
    double s = 0.0;
    for (int k = 0; k <= la + lb - lc; ++k) {
      int d2 = la - m1 - k, d3 = lb + m2 - k, d4 = lc - lb + m1 + k, d5 = lc - la - m2 + k;
      if (d2 < 0 || d3 < 0 || d4 < 0 || d5 < 0) continue;
      s += ((k & 1) ? -1.0 : 1.0) /
           (sfact[k]*sfact[la+lb-lc-k]*sfact[d2]*sfact[d3]*sfact[d4]*sfact[d5]);
    }
    sC[(i*nb + j)*nc + (lc + m3)] = pre * s;
  }
  __syncthreads();
  const double PH = (((la/2)&1)?-1.0:1.0)*(((lb/2)&1)?-1.0:1.0)*(((lc/2)&1)?-1.0:1.0);
  const double scale = 0.5 * (double)tpw[p] * PH;
  for (int e = threadIdx.x; e < na*nb*ncp; e += blockDim.x) {
    int a = e / (nb*ncp), rem = e % (nb*ncp), b = rem / ncp, c = rem % ncp;
    float val = 0.0f;
    if (c < nc) {
      int r1[2]; double u1r[2], u1i[2]; int n1 = qcol(la, a, r1, u1r, u1i);
      int r2[2]; double u2r[2], u2i[2]; int n2 = qcol(lb, b, r2, u2r, u2i);
      int r3[2]; double u3r[2], u3i[2]; int n3 = qcol(lc, c, r3, u3r, u3i);
      double acc = 0.0;
      for (int u = 0; u < n1; ++u)
        for (int v = 0; v < n2; ++v) {
          double Rr = u1r[u]*u2r[v] - u1i[u]*u2i[v];
          double Ri = u1r[u]*u2i[v] + u1i[u]*u2r[v];
          for (int w = 0; w < n3; ++w) {
            double cv = sC[(r1[u]*nb + r2[v])*nc + r3[w]];
            acc += (Rr*u3r[w] + Ri*u3i[w]) * cv;
          }
        }
      val = (float)(scale * acc);
    }
    coef[off + e] = val;
  }
}

// ---------------------------------------------------------------------------
// Repack f4/f6 into 16B-aligned, k-layout-matched xp[pix][28]:
// word w: w<9 -> f4 comp w; 12<=w<25 -> f6 comp w-12; else 0.
// ---------------------------------------------------------------------------
__global__ __launch_bounds__(256) void repack_x(const float* __restrict__ f4,
                                                const float* __restrict__ f6,
                                                float* __restrict__ xp) {
  int t = blockIdx.x * 256 + threadIdx.x;   // 16384*28 = 458752 = 1792*256
  int pix = t / 28, w = t % 28;
  float v = 0.0f;
  if (w < 9) v = f4[pix*9 + w];
  else if (w >= 12 && w < 25) v = f6[pix*13 + (w - 12)];
  xp[t] = v;
}

// extract the 22 feature scalars from one packed pixel (static indexing only)
struct XV { float v[22]; };
static __device__ __forceinline__ XV load_x(const float* __restrict__ xb) {
  XV r;
  float4 q0 = *(const float4*)(xb);
  float4 q1 = *(const float4*)(xb + 4);
  float4 q2 = *(const float4*)(xb + 8);
  float4 q3 = *(const float4*)(xb + 12);
  float4 q4 = *(const float4*)(xb + 16);
  float4 q5 = *(const float4*)(xb + 20);
  float4 q6 = *(const float4*)(xb + 24);
  r.v[0]=q0.x;  r.v[1]=q0.y;  r.v[2]=q0.z;  r.v[3]=q0.w;
  r.v[4]=q1.x;  r.v[5]=q1.y;  r.v[6]=q1.z;  r.v[7]=q1.w;
  r.v[8]=q2.x;
  r.v[9]=q3.x;  r.v[10]=q3.y; r.v[11]=q3.z; r.v[12]=q3.w;
  r.v[13]=q4.x; r.v[14]=q4.y; r.v[15]=q4.z; r.v[16]=q4.w;
  r.v[17]=q5.x; r.v[18]=q5.y; r.v[19]=q5.z; r.v[20]=q5.w;
  r.v[21]=q6.x;
  return r;
}

// ---------------------------------------------------------------------------
// Main kernel. Block = 16 low-res pixels in a row (256 threads, 1024 blocks).
// P1 (154 thr): M[p][j][kq] = sum_i C[i][j][kq] x_p[i]  (coef in regs, x from global)
// P2 (112 thr): z[p][nb][kq] = sum_j x_nb[j] M[p][j][kq] for 9 neighbors
// P3 (256 thr): out = A00*z_C + A01*z_col + A10*z_row + A11*z_diag + x_p
// ---------------------------------------------------------------------------
__global__ __launch_bounds__(256) void eqconv_main(
    const float* __restrict__ xp, const float* __restrict__ sw,
    const float* __restrict__ coef, float* __restrict__ out) {
  __shared__ float M_lds[16 * MS];   // 39.7 KB
  __shared__ float z_lds[16 * ZS];   // 16.1 KB

  const int tid = threadIdx.x;
  const int ry  = blockIdx.x >> 3;
  const int cx0 = (blockIdx.x & 7) * 16;

  // ---------------- P1 ----------------
  if (tid < 154) {
    int cls, jj, kqc;
    if (tid < 27)       { cls = 0; jj = tid / 3;         kqc = tid % 3; }
    else if (tid < 63)  { cls = 1; jj = (tid - 27) / 4;  kqc = (tid - 27) % 4; }
    else if (tid < 102) { cls = 2; jj = (tid - 63) / 3;  kqc = (tid - 63) % 3; }
    else                { cls = 3; jj = (tid - 102) / 4; kqc = (tid - 102) % 4; }
    const int ncp  = (cls == 0 || cls == 2) ? 12 : 16;
    const int str  = (cls == 0) ? 108 : (cls == 1) ? 144 : (cls == 2) ? 156 : 208;
    const int off4 = (cls == 0) ? 0    : (cls == 1) ? 972  : (cls == 2) ? 2268 : 3672;
    const int off6 = (cls == 0) ? 5544 : (cls == 1) ? 6948 : (cls == 2) ? 8820 : 10848;
    const int base4 = off4 + jj*ncp + 4*kqc;
    const int base6 = off6 + jj*ncp + 4*kqc;
    const int j   = (cls >= 2) ? 9 + jj : jj;
    const int kqu = (cls == 0 || cls == 2) ? kqc : 3 + kqc;

    float4 cR[22];
#pragma unroll
    for (int i = 0; i < 9; ++i)  cR[i]     = *(const float4*)(coef + base4 + i*str);
#pragma unroll
    for (int i = 0; i < 13; ++i) cR[9 + i] = *(const float4*)(coef + base6 + i*str);

    const int mo = j*28 + kqu*4;
    const int pixbase = ry*128 + cx0;
#pragma unroll
    for (int p = 0; p < 16; ++p) {
      XV x = load_x(xp + (pixbase + p)*28);
      float4 a = make_float4(0.f, 0.f, 0.f, 0.f);
#pragma unroll
      for (int i = 0; i < 22; ++i) {
        a.x = fmaf(cR[i].x, x.v[i], a.x);
        a.y = fmaf(cR[i].y, x.v[i], a.y);
        a.z = fmaf(cR[i].z, x.v[i], a.z);
        a.w = fmaf(cR[i].w, x.v[i], a.w);
      }
      *(float4*)(&M_lds[p*MS + mo]) = a;
    }
  }
  __syncthreads();

  // ---------------- P2 ----------------
  if (tid < 112) {
    const int p  = tid / 7, kq = tid % 7;
    const float* Mb = &M_lds[p*MS + 4*kq];
    float4 m[22];
#pragma unroll
    for (int jx = 0; jx < 22; ++jx) m[jx] = *(const float4*)(Mb + jx*28);
    const int cx = cx0 + p;
    float* zb = &z_lds[p*ZS + 4*kq];
#pragma unroll
    for (int rs = 0; rs < 3; ++rs) {
      const int rr = min(127, max(0, ry + rs - 1));
#pragma unroll
      for (int cs = 0; cs < 3; ++cs) {
        const int cc = min(127, max(0, cx + cs - 1));
        XV x = load_x(xp + (rr*128 + cc)*28);
        float4 a = make_float4(0.f, 0.f, 0.f, 0.f);
#pragma unroll
        for (int jx = 0; jx < 22; ++jx) {
          a.x = fmaf(m[jx].x, x.v[jx], a.x);
          a.y = fmaf(m[jx].y, x.v[jx], a.y);
          a.z = fmaf(m[jx].z, x.v[jx], a.z);
          a.w = fmaf(m[jx].w, x.v[jx], a.w);
        }
        *(float4*)(zb + (rs*3 + cs)*28) = a;
      }
    }
  }
  __syncthreads();

  // ---------------- P3 ----------------
  {
    const int p  = tid >> 4;
    const int w  = tid & 15;
    const int dy = w >> 2, dx = w & 3;
    const int cx = cx0 + p;
    const int Yh = ry*4 + dy, Xh = cx*4 + dx;

    const int rm = (Yh == 0)   ? ry : ((Yh - 1) >> 2);
    const int rp = (Yh == 511) ? ry : ((Yh + 1) >> 2);
    const int cm = (Xh == 0)   ? cx : ((Xh - 1) >> 2);
    const int cp = (Xh == 511) ? cx : ((Xh + 1) >> 2);
    const int sR0 = (rm != ry) ? 1 : 0, sR2 = (rp != ry) ? 1 : 0;
    const int sC0 = (cm != cx) ? 1 : 0, sC2 = (cp != cx) ? 1 : 0;

    float A00 = 0.f, A01 = 0.f, A10 = 0.f, A11 = 0.f;
#pragma unroll
    for (int ddy = 0; ddy < 3; ++ddy) {
      const int rs = (ddy == 0) ? sR0 : ((ddy == 2) ? sR2 : 0);
#pragma unroll
      for (int ddx = 0; ddx < 3; ++ddx) {
        const int cs = (ddx == 0) ? sC0 : ((ddx == 2) ? sC2 : 0);
        const float ww = sw[ddy*3 + ddx];
        A00 += (rs == 0 && cs == 0) ? ww : 0.f;
        A01 += (rs == 0 && cs != 0) ? ww : 0.f;
        A10 += (rs != 0 && cs == 0) ? ww : 0.f;
        A11 += (rs != 0 && cs != 0) ? ww : 0.f;
      }
    }

    // neighbor slots: nb = rowSel*3 + colSel, C=4
    const int colnb = (dx == 0) ? 3 : 5;
    const int rownb = (dy == 0) ? 1 : 7;
    const int dianb = ((dy == 0) ? 0 : 6) + ((dx == 0) ? 0 : 2);

    const float* zb = &z_lds[p*ZS];
    const float* xb = xp + (ry*128 + cx)*28;

    float4 acc[7];
#pragma unroll
    for (int kq = 0; kq < 7; ++kq) {
      float4 zc = *(const float4*)(zb + 4*28    + 4*kq);
      float4 z1 = *(const float4*)(zb + colnb*28 + 4*kq);
      float4 z2 = *(const float4*)(zb + rownb*28 + 4*kq);
      float4 z3 = *(const float4*)(zb + dianb*28 + 4*kq);
      float4 xr = *(const float4*)(xb + 4*kq);
      float4 a;
      a.x = fmaf(A00, zc.x, fmaf(A01, z1.x, fmaf(A10, z2.x, fmaf(A11, z3.x, xr.x))));
      a.y = fmaf(A00, zc.y, fmaf(A01, z1.y, fmaf(A10, z2.y, fmaf(A11, z3.y, xr.y))));
      a.z = fmaf(A00, zc.z, fmaf(A01, z1.z, fmaf(A10, z2.z, fmaf(A11, z3.z, xr.z))));
      a.w = fmaf(A00, zc.w, fmaf(A01, z1.w, fmaf(A10, z2.w, fmaf(A11, z3.w, xr.w))));
      acc[kq] = a;
    }

    const int n = Yh*512 + Xh;
    float* o4 = out + n*9;
    o4[0] = acc[0].x; o4[1] = acc[0].y; o4[2] = acc[0].z; o4[3] = acc[0].w;
    o4[4] = acc[1].x; o4[5] = acc[1].y; o4[6] = acc[1].z; o4[7] = acc[1].w;
    o4[8] = acc[2].x;
    float* o6 = out + NPIX*9 + n*13;
    o6[0]  = acc[3].x; o6[1]  = acc[3].y; o6[2]  = acc[3].z; o6[3]  = acc[3].w;
    o6[4]  = acc[4].x; o6[5]  = acc[4].y; o6[6]  = acc[4].z; o6[7]  = acc[4].w;
    o6[8]  = acc[5].x; o6[9]  = acc[5].y; o6[10] = acc[5].z; o6[11] = acc[5].w;
    o6[12] = acc[6].x;
  }
}

extern "C" void kernel_launch(void* const* d_in, const int* in_sizes, int n_in,
                              void* d_out, int out_size, void* d_ws, size_t ws_size,
                              hipStream_t stream) {
  const float* f4  = (const float*)d_in[0];
  const float* f6  = (const float*)d_in[1];
  const float* sw  = (const float*)d_in[2];
  const float* tpw = (const float*)d_in[3];
  float* coef = (float*)d_ws;                 // 13552 floats
  float* xpk  = (float*)d_ws + 16384;         // 458752 floats, 16B-aligned
  float* out  = (float*)d_out;

  hipLaunchKernelGGL(w3j_init, dim3(8), dim3(256), 0, stream, tpw, coef);
  hipLaunchKernelGGL(repack_x, dim3(1792), dim3(256), 0, stream, f4, f6, xpk);
  hipLaunchKernelGGL(eqconv_main, dim3(1024), dim3(256), 0, stream, xpk, sw, coef, out);
}